// Round 2
// baseline (1068.361 us; speedup 1.0000x reference)
//
#include <hip/hip_runtime.h>
#include <hip/hip_bf16.h>

typedef __hip_bfloat16 bf16;
#define HIDC 128

// dtype-adaptive load: element i of a float array whose on-device dtype is
// unknown at compile time (f32=1 -> float32, f32=0 -> bf16).
__device__ __forceinline__ float ldf(const void* p, size_t i, int f32) {
    if (f32) return ((const float*)p)[i];
    return __bfloat162float(((const bf16*)p)[i]);
}

// ---- dtype probe: bf16 view of a weight array; float32 data shows |v|>1e4 ----
__global__ void __launch_bounds__(256) r2_probe_dtype(const void* w, int n, int* flag)
{
    __shared__ float red[256];
    int t = threadIdx.x;
    float m = 0.f;
    const bf16* p = (const bf16*)w;
    for (int i = t; i < n; i += 256) {
        float v = fabsf(__bfloat162float(p[i]));
        if (!(v <= 1e30f)) v = 1e30f;   // NaN/Inf -> huge
        m = fmaxf(m, v);
    }
    red[t] = m; __syncthreads();
    for (int off = 128; off > 0; off >>= 1) { if (t < off) red[t] = fmaxf(red[t], red[t + off]); __syncthreads(); }
    if (t == 0) flag[0] = (red[0] > 1e4f) ? 1 : 0;
}

__global__ void __launch_bounds__(256) r2_zero(int* p, int n)
{
    int i = blockIdx.x * 256 + threadIdx.x;
    if (i < n) p[i] = 0;
}

// ---------------- node GEMM: H[row] = emb[idx[row]] @ W ; s = H·a ----------------
template <int F32>
__global__ void __launch_bounds__(128) r2_node_gemm(
    const void* __restrict__ emb, const int* __restrict__ idx, const void* __restrict__ W,
    const void* __restrict__ a_src, const void* __restrict__ a_dst,
    float* __restrict__ H, float* __restrict__ s_src, float* __restrict__ s_dst,
    const int* __restrict__ dtf)
{
    if (dtf[0] != F32) return;   // uniform early exit: wrong-dtype variant
    int row = blockIdx.x;
    int c = threadIdx.x;
    __shared__ float xs[HIDC];
    __shared__ float red[HIDC];
    int nid = idx[row];
    xs[c] = ldf(emb, (size_t)nid * HIDC + c, F32);
    __syncthreads();
    float acc = 0.f;
#pragma unroll 8
    for (int k = 0; k < HIDC; k++) acc = fmaf(xs[k], ldf(W, (size_t)k * HIDC + c, F32), acc);
    if (H) H[(size_t)row * HIDC + c] = acc;
    if (a_src) {
        red[c] = acc * ldf(a_src, c, F32); __syncthreads();
#pragma unroll
        for (int off = 64; off > 0; off >>= 1) { if (c < off) red[c] += red[c + off]; __syncthreads(); }
        if (c == 0) s_src[row] = red[0];
        __syncthreads();
    }
    if (a_dst) {
        red[c] = acc * ldf(a_dst, c, F32); __syncthreads();
#pragma unroll
        for (int off = 64; off > 0; off >>= 1) { if (c < off) red[c] += red[c + off]; __syncthreads(); }
        if (c == 0) s_dst[row] = red[0];
    }
}

// ---------------- scalar dot of two length-128 vectors ----------------
__global__ void __launch_bounds__(128) r2_dot128(const void* a, const void* b, float* out,
                                                 const int* __restrict__ dtf)
{
    const int f32 = dtf[0];
    __shared__ float red[HIDC];
    int c = threadIdx.x;
    red[c] = ldf(a, c, f32) * ldf(b, c, f32); __syncthreads();
#pragma unroll
    for (int off = 64; off > 0; off >>= 1) { if (c < off) red[c] += red[c + off]; __syncthreads(); }
    if (c == 0) out[0] = red[0];
}

// ---------------- d-d preprocessing: deg + attr_sum ----------------
__global__ void r2_dd_pre(const int* __restrict__ ei, const void* __restrict__ attr, int E,
                          int* __restrict__ deg, float* __restrict__ attr_sum,
                          const int* __restrict__ dtf)
{
    const int f32 = dtf[0];
    int e = blockIdx.x * 256 + threadIdx.x;
    if (e >= E) return;
    int d = ei[E + e];
    atomicAdd(&deg[d], 1);
    atomicAdd(&attr_sum[d], ldf(attr, e, f32));
}

__global__ void r2_dd_finalize(const int* __restrict__ deg, float* __restrict__ attr_sum,
                               int* __restrict__ cnt, int n)
{
    int d = blockIdx.x * 256 + threadIdx.x;
    if (d >= n) return;
    int dg = deg[d];
    cnt[d] = dg + 1;
    attr_sum[d] = attr_sum[d] / fmaxf((float)dg, 1.0f);
}

__global__ void r2_count(const int* __restrict__ dst, int E, int* __restrict__ cnt)
{
    int e = blockIdx.x * 256 + threadIdx.x;
    if (e >= E) return;
    atomicAdd(&cnt[dst[e]], 1);
}

// ---------------- single-block exclusive scan ----------------
__global__ void __launch_bounds__(1024) r2_exscan(const int* __restrict__ in, int* __restrict__ out, int n)
{
    __shared__ int buf[1024];
    __shared__ int carry;
    int tid = threadIdx.x;
    if (tid == 0) carry = 0;
    __syncthreads();
    for (int base = 0; base < n; base += 1024) {
        int i = base + tid;
        int v = (i < n) ? in[i] : 0;
        buf[tid] = v; __syncthreads();
        for (int off = 1; off < 1024; off <<= 1) {
            int t = (tid >= off) ? buf[tid - off] : 0;
            __syncthreads();
            buf[tid] += t;
            __syncthreads();
        }
        int c0 = carry;
        int incl = buf[tid];
        if (i < n) out[i] = c0 + incl - v;
        __syncthreads();
        if (tid == 1023) carry = c0 + buf[1023];
        __syncthreads();
    }
    if (tid == 0) out[n] = carry;
}

// ---------------- CSR fill: e = leaky(s_src[src]+s_dst[dst]+attr*c_edge) ----------------
__global__ void r2_fill_edges(const int* __restrict__ src, const int* __restrict__ dst, int E,
                              const float* __restrict__ s_src, const float* __restrict__ s_dst,
                              const void* __restrict__ attr, int use_attr,
                              const float* __restrict__ c_edge_ptr,
                              const int* __restrict__ row_start, int* __restrict__ cursor,
                              int* __restrict__ csr_src, float* __restrict__ csr_e,
                              const int* __restrict__ dtf)
{
    const int f32 = dtf[0];
    int e = blockIdx.x * 256 + threadIdx.x;
    if (e >= E) return;
    int s = src[e], d = dst[e];
    float ev = s_src[s] + s_dst[d];
    if (use_attr) ev += ldf(attr, e, f32) * c_edge_ptr[0];
    ev = (ev > 0.f) ? ev : 0.2f * ev;
    int slot = row_start[d] + atomicAdd(&cursor[d], 1);
    csr_src[slot] = s;
    csr_e[slot] = ev;
}

__global__ void r2_fill_self(int n, const float* __restrict__ s_src, const float* __restrict__ s_dst,
                             const float* __restrict__ mean_attr, const float* __restrict__ c_edge_ptr,
                             const int* __restrict__ row_start, int* __restrict__ cursor,
                             int* __restrict__ csr_src, float* __restrict__ csr_e)
{
    int d = blockIdx.x * 256 + threadIdx.x;
    if (d >= n) return;
    float ev = s_src[d] + s_dst[d] + mean_attr[d] * c_edge_ptr[0];
    ev = (ev > 0.f) ? ev : 0.2f * ev;
    int slot = row_start[d] + atomicAdd(&cursor[d], 1);
    csr_src[slot] = d;
    csr_e[slot] = ev;
}

// ---------------- per-dst softmax + aggregate ----------------
__global__ void __launch_bounds__(128) r2_gat_aggregate(
    const int* __restrict__ row_start, const int* __restrict__ csr_src, const float* __restrict__ csr_e,
    const float* __restrict__ H, float* __restrict__ out)
{
    int row = blockIdx.x;
    int c = threadIdx.x;
    int s = row_start[row], e = row_start[row + 1];
    __shared__ float red[HIDC];
    __shared__ float se[HIDC];
    __shared__ int ss[HIDC];
    float m = -INFINITY;
    for (int i = s + c; i < e; i += HIDC) m = fmaxf(m, csr_e[i]);
    red[c] = m; __syncthreads();
#pragma unroll
    for (int off = 64; off > 0; off >>= 1) { if (c < off) red[c] = fmaxf(red[c], red[c + off]); __syncthreads(); }
    m = red[0]; __syncthreads();
    float sum = 0.f;
    for (int i = s + c; i < e; i += HIDC) sum += __expf(csr_e[i] - m);
    red[c] = sum; __syncthreads();
#pragma unroll
    for (int off = 64; off > 0; off >>= 1) { if (c < off) red[c] += red[c + off]; __syncthreads(); }
    float denom = red[0]; __syncthreads();
    float acc = 0.f;
    for (int base = s; base < e; base += HIDC) {
        int i = base + c;
        if (i < e) { se[c] = __expf(csr_e[i] - m); ss[c] = csr_src[i]; }
        __syncthreads();
        int lim = min(HIDC, e - base);
        for (int j = 0; j < lim; j++)
            acc = fmaf(se[j], H[(size_t)ss[j] * HIDC + c], acc);
        __syncthreads();
    }
    out[(size_t)row * HIDC + c] = acc / (denom + 1e-16f);
}

// ---------------- combine + relu + L2 normalize ----------------
__global__ void __launch_bounds__(128) r2_fuse_drug(
    const float* __restrict__ agg_dd, const void* __restrict__ bias_dd,
    const float* __restrict__ agg_dp, const void* __restrict__ bias_dp,
    float* __restrict__ outN, const int* __restrict__ dtf)
{
    const int f32 = dtf[0];
    int d = blockIdx.x, c = threadIdx.x;
    float v = agg_dd[(size_t)d * HIDC + c] + ldf(bias_dd, c, f32)
            + agg_dp[(size_t)d * HIDC + c] + ldf(bias_dp, c, f32);
    v = fmaxf(v, 0.f);
    __shared__ float red[HIDC];
    red[c] = v * v; __syncthreads();
#pragma unroll
    for (int off = 64; off > 0; off >>= 1) { if (c < off) red[c] += red[c + off]; __syncthreads(); }
    float nrm = fmaxf(sqrtf(red[0]), 1e-12f);
    outN[(size_t)d * HIDC + c] = v / nrm;
}

__global__ void __launch_bounds__(128) r2_fuse_cell(
    const float* __restrict__ agg_cp, const void* __restrict__ bias_cp,
    float* __restrict__ outN, const int* __restrict__ dtf)
{
    const int f32 = dtf[0];
    int d = blockIdx.x, c = threadIdx.x;
    float v = agg_cp[(size_t)d * HIDC + c] + ldf(bias_cp, c, f32);
    v = fmaxf(v, 0.f);
    __shared__ float red[HIDC];
    red[c] = v * v; __syncthreads();
#pragma unroll
    for (int off = 64; off > 0; off >>= 1) { if (c < off) red[c] += red[c + off]; __syncthreads(); }
    float nrm = fmaxf(sqrtf(red[0]), 1e-12f);
    outN[(size_t)d * HIDC + c] = v / nrm;
}

// ---------------- hid gather ----------------
__global__ void __launch_bounds__(128) r2_gather_hid(
    const float* __restrict__ drugN, const float* __restrict__ cellN,
    const int* __restrict__ d1, const int* __restrict__ d2, const int* __restrict__ ce,
    float* __restrict__ hid)
{
    int b = blockIdx.x, c = threadIdx.x;
    hid[(size_t)b * 384 + c]       = drugN[(size_t)d1[b] * HIDC + c];
    hid[(size_t)b * 384 + 128 + c] = drugN[(size_t)d2[b] * HIDC + c];
    hid[(size_t)b * 384 + 256 + c] = cellN[(size_t)ce[b] * HIDC + c];
}

// ---------------- MLP GEMM: 16 rows/block, 256 threads, COLS cols/thread ----------------
template <int COLS, int F32>
__global__ void __launch_bounds__(256) r2_mlp_gemm(
    const float* __restrict__ X, const void* __restrict__ W, const void* __restrict__ bias,
    float* __restrict__ Y, int K, int N, int do_relu, const int* __restrict__ dtf)
{
    if (dtf[0] != F32) return;
    constexpr int ROWS = 16;
    extern __shared__ float xs[];
    int r0 = blockIdx.x * ROWS;
    for (int t = threadIdx.x; t < ROWS * K; t += 256) {
        int r = t / K, k = t - r * K;
        xs[k * ROWS + r] = X[(size_t)(r0 + r) * K + k];
    }
    __syncthreads();
    int c = threadIdx.x;
    float acc[ROWS][COLS];
#pragma unroll
    for (int r = 0; r < ROWS; r++)
#pragma unroll
        for (int j = 0; j < COLS; j++) acc[r][j] = 0.f;

#pragma unroll 4
    for (int k = 0; k < K; k++) {
        float w[COLS];
#pragma unroll
        for (int j = 0; j < COLS; j++) w[j] = ldf(W, (size_t)k * N + c + j * 256, F32);
        const float* xr = &xs[k * ROWS];
#pragma unroll
        for (int r = 0; r < ROWS; r++) {
            float xv = xr[r];
#pragma unroll
            for (int j = 0; j < COLS; j++) acc[r][j] = fmaf(xv, w[j], acc[r][j]);
        }
    }
#pragma unroll
    for (int j = 0; j < COLS; j++) {
        float bv = ldf(bias, c + j * 256, F32);
#pragma unroll
        for (int r = 0; r < ROWS; r++) {
            float v = acc[r][j] + bv;
            if (do_relu) v = fmaxf(v, 0.f);
            Y[(size_t)(r0 + r) * N + c + j * 256] = v;
        }
    }
}

// ---------------- final 256->2 GEMM, wave per row ----------------
__global__ void __launch_bounds__(256) r2_final(
    const float* __restrict__ h2, const void* __restrict__ W3, const void* __restrict__ b3,
    void* __restrict__ out, const int* __restrict__ dtf)
{
    const int f32 = dtf[0];
    int row = blockIdx.x * 4 + (threadIdx.x >> 6);
    int lane = threadIdx.x & 63;
    float a0 = 0.f, a1 = 0.f;
    for (int k = lane; k < 256; k += 64) {
        float h = h2[(size_t)row * 256 + k];
        a0 = fmaf(h, ldf(W3, k * 2 + 0, f32), a0);
        a1 = fmaf(h, ldf(W3, k * 2 + 1, f32), a1);
    }
#pragma unroll
    for (int off = 32; off > 0; off >>= 1) {
        a0 += __shfl_down(a0, off, 64);
        a1 += __shfl_down(a1, off, 64);
    }
    if (lane == 0) {
        float o0 = a0 + ldf(b3, 0, f32);
        float o1 = a1 + ldf(b3, 1, f32);
        if (f32) {
            ((float*)out)[row * 2 + 0] = o0;
            ((float*)out)[row * 2 + 1] = o1;
        } else {
            ((bf16*)out)[row * 2 + 0] = __float2bfloat16(o0);
            ((bf16*)out)[row * 2 + 1] = __float2bfloat16(o1);
        }
    }
}

extern "C" void kernel_launch(void* const* d_in, const int* in_sizes, int n_in,
                              void* d_out, int out_size, void* d_ws, size_t ws_size,
                              hipStream_t stream)
{
    const int* x_drug      = (const int*)d_in[0];
    const int* x_protein   = (const int*)d_in[1];
    const int* x_cell      = (const int*)d_in[2];
    const int* ei_dd       = (const int*)d_in[3];
    const void* attr_dd    = d_in[4];
    const int* src_dp      = (const int*)d_in[5];
    const int* dst_dp      = (const int*)d_in[6];
    const int* src_cp      = (const int*)d_in[7];
    const int* dst_cp      = (const int*)d_in[8];
    const int* drug1       = (const int*)d_in[9];
    const int* drug2       = (const int*)d_in[10];
    const int* cellb       = (const int*)d_in[11];
    const void* drug_emb   = d_in[12];
    const void* protein_emb= d_in[13];
    const void* cell_emb   = d_in[14];
    const void* W_dd       = d_in[15];
    const void* a_src_dd   = d_in[16];
    const void* a_dst_dd   = d_in[17];
    const void* bias_dd    = d_in[18];
    const void* W_edge_dd  = d_in[19];
    const void* a_edge_dd  = d_in[20];
    const void* W_dp       = d_in[21];
    const void* a_src_dp   = d_in[22];
    const void* a_dst_dp   = d_in[23];
    const void* bias_dp    = d_in[24];
    const void* W_cp       = d_in[25];
    const void* a_src_cp   = d_in[26];
    const void* a_dst_cp   = d_in[27];
    const void* bias_cp    = d_in[28];
    const void* W1         = d_in[29];
    const void* b1         = d_in[30];
    const void* W2         = d_in[31];
    const void* b2         = d_in[32];
    const void* W3         = d_in[33];
    const void* b3         = d_in[34];

    const int ND  = in_sizes[0];
    const int NPR = in_sizes[1];
    const int NCL = in_sizes[2];
    const int E_DD = in_sizes[4];
    const int E_DP = in_sizes[5];
    const int E_CP = in_sizes[7];
    const int B    = in_sizes[9];
    const int E_DD2 = E_DD + ND;

    // ---- carve workspace ----
    char* p = (char*)d_ws;
    auto carve = [&](size_t bytes) -> char* {
        char* r = p;
        p += (bytes + 255) & ~(size_t)255;
        return r;
    };
    int* dt_flag = (int*)carve(256);   // written by probe, read by all
    // zeroed region
    char* zstart = p;
    int*   deg      = (int*)  carve((size_t)ND * 4);
    float* attr_sum = (float*)carve((size_t)ND * 4);
    int*   cnt_dp   = (int*)  carve((size_t)ND * 4);
    int*   cnt_cp   = (int*)  carve((size_t)NCL * 4);
    int*   cur_dd   = (int*)  carve((size_t)ND * 4);
    int*   cur_dp   = (int*)  carve((size_t)ND * 4);
    int*   cur_cp   = (int*)  carve((size_t)NCL * 4);
    size_t zbytes = (size_t)(p - zstart);
    // non-zeroed
    int*   cnt_dd   = (int*)  carve((size_t)ND * 4);
    int*   rs_dd    = (int*)  carve((size_t)(ND + 1) * 4);
    int*   rs_dp    = (int*)  carve((size_t)(ND + 1) * 4);
    int*   rs_cp    = (int*)  carve((size_t)(NCL + 1) * 4);
    float* c_edge   = (float*)carve(256);
    float* H_dd     = (float*)carve((size_t)ND * HIDC * 4);
    float* H_dp     = (float*)carve((size_t)NPR * HIDC * 4);
    float* H_cp     = (float*)carve((size_t)NPR * HIDC * 4);
    float* ssrc_dd  = (float*)carve((size_t)ND * 4);
    float* sdst_dd  = (float*)carve((size_t)ND * 4);
    float* ssrc_dp  = (float*)carve((size_t)NPR * 4);
    float* sdst_dp  = (float*)carve((size_t)ND * 4);
    float* ssrc_cp  = (float*)carve((size_t)NPR * 4);
    float* sdst_cp  = (float*)carve((size_t)NCL * 4);
    int*   csrc_dd  = (int*)  carve((size_t)E_DD2 * 4);
    float* ce_dd    = (float*)carve((size_t)E_DD2 * 4);
    int*   csrc_dp  = (int*)  carve((size_t)E_DP * 4);
    float* ce_dp    = (float*)carve((size_t)E_DP * 4);
    int*   csrc_cp  = (int*)  carve((size_t)E_CP * 4);
    float* ce_cp    = (float*)carve((size_t)E_CP * 4);
    float* agg_dd   = (float*)carve((size_t)ND * HIDC * 4);
    float* agg_dp   = (float*)carve((size_t)ND * HIDC * 4);
    float* agg_cp   = (float*)carve((size_t)NCL * HIDC * 4);
    float* drugN    = (float*)carve((size_t)ND * HIDC * 4);
    float* cellN    = (float*)carve((size_t)NCL * HIDC * 4);
    float* hid      = (float*)carve((size_t)B * 384 * 4);
    float* h1       = (float*)carve((size_t)B * 768 * 4);
    float* h2       = hid;  // hid dead after MLP layer 1; B*256 <= B*384

    auto cdiv = [](int a, int b) { return (a + b - 1) / b; };
    const int* dtf = dt_flag;

    // ---- dtype probe + zero-init ----
    r2_probe_dtype<<<1, 256, 0, stream>>>(W1, 4096, dt_flag);
    int zwords = (int)(zbytes / 4);
    r2_zero<<<cdiv(zwords, 256), 256, 0, stream>>>((int*)zstart, zwords);

    // ---- node GEMMs + attention scalars (both dtype variants; wrong one exits) ----
#define NODE_GEMM(GRID, EMB, IDX, WW, AS, AD, HH, SS, SD) \
    r2_node_gemm<0><<<GRID, 128, 0, stream>>>(EMB, IDX, WW, AS, AD, HH, SS, SD, dtf); \
    r2_node_gemm<1><<<GRID, 128, 0, stream>>>(EMB, IDX, WW, AS, AD, HH, SS, SD, dtf);

    NODE_GEMM(ND,  drug_emb,    x_drug,    W_dd, a_src_dd, a_dst_dd, H_dd, ssrc_dd, sdst_dd)
    NODE_GEMM(NPR, protein_emb, x_protein, W_dp, a_src_dp, (const void*)nullptr, H_dp, ssrc_dp, (float*)nullptr)
    NODE_GEMM(ND,  drug_emb,    x_drug,    W_dp, (const void*)nullptr, a_dst_dp, (float*)nullptr, (float*)nullptr, sdst_dp)
    NODE_GEMM(NPR, protein_emb, x_protein, W_cp, a_src_cp, (const void*)nullptr, H_cp, ssrc_cp, (float*)nullptr)
    NODE_GEMM(NCL, cell_emb,    x_cell,    W_cp, (const void*)nullptr, a_dst_cp, (float*)nullptr, (float*)nullptr, sdst_cp)
#undef NODE_GEMM

    r2_dot128<<<1, 128, 0, stream>>>(W_edge_dd, a_edge_dd, c_edge, dtf);

    // ---- degrees / counts ----
    r2_dd_pre<<<cdiv(E_DD, 256), 256, 0, stream>>>(ei_dd, attr_dd, E_DD, deg, attr_sum, dtf);
    r2_dd_finalize<<<cdiv(ND, 256), 256, 0, stream>>>(deg, attr_sum, cnt_dd, ND);
    r2_count<<<cdiv(E_DP, 256), 256, 0, stream>>>(dst_dp, E_DP, cnt_dp);
    r2_count<<<cdiv(E_CP, 256), 256, 0, stream>>>(dst_cp, E_CP, cnt_cp);

    // ---- CSR row starts ----
    r2_exscan<<<1, 1024, 0, stream>>>(cnt_dd, rs_dd, ND);
    r2_exscan<<<1, 1024, 0, stream>>>(cnt_dp, rs_dp, ND);
    r2_exscan<<<1, 1024, 0, stream>>>(cnt_cp, rs_cp, NCL);

    // ---- CSR fill ----
    r2_fill_edges<<<cdiv(E_DD, 256), 256, 0, stream>>>(ei_dd, ei_dd + E_DD, E_DD, ssrc_dd, sdst_dd,
                                                       attr_dd, 1, c_edge, rs_dd, cur_dd, csrc_dd, ce_dd, dtf);
    r2_fill_self<<<cdiv(ND, 256), 256, 0, stream>>>(ND, ssrc_dd, sdst_dd, attr_sum, c_edge,
                                                    rs_dd, cur_dd, csrc_dd, ce_dd);
    r2_fill_edges<<<cdiv(E_DP, 256), 256, 0, stream>>>(src_dp, dst_dp, E_DP, ssrc_dp, sdst_dp,
                                                       nullptr, 0, c_edge, rs_dp, cur_dp, csrc_dp, ce_dp, dtf);
    r2_fill_edges<<<cdiv(E_CP, 256), 256, 0, stream>>>(src_cp, dst_cp, E_CP, ssrc_cp, sdst_cp,
                                                       nullptr, 0, c_edge, rs_cp, cur_cp, csrc_cp, ce_cp, dtf);

    // ---- softmax + aggregate ----
    r2_gat_aggregate<<<ND, 128, 0, stream>>>(rs_dd, csrc_dd, ce_dd, H_dd, agg_dd);
    r2_gat_aggregate<<<ND, 128, 0, stream>>>(rs_dp, csrc_dp, ce_dp, H_dp, agg_dp);
    r2_gat_aggregate<<<NCL, 128, 0, stream>>>(rs_cp, csrc_cp, ce_cp, H_cp, agg_cp);

    // ---- combine + relu + L2 normalize ----
    r2_fuse_drug<<<ND, 128, 0, stream>>>(agg_dd, bias_dd, agg_dp, bias_dp, drugN, dtf);
    r2_fuse_cell<<<NCL, 128, 0, stream>>>(agg_cp, bias_cp, cellN, dtf);

    // ---- batch gather + MLP ----
    r2_gather_hid<<<B, 128, 0, stream>>>(drugN, cellN, drug1, drug2, cellb, hid);
    r2_mlp_gemm<3, 0><<<B / 16, 256, 16 * 384 * 4, stream>>>(hid, W1, b1, h1, 384, 768, 1, dtf);
    r2_mlp_gemm<3, 1><<<B / 16, 256, 16 * 384 * 4, stream>>>(hid, W1, b1, h1, 384, 768, 1, dtf);
    r2_mlp_gemm<1, 0><<<B / 16, 256, 16 * 768 * 4, stream>>>(h1, W2, b2, h2, 768, 256, 1, dtf);
    r2_mlp_gemm<1, 1><<<B / 16, 256, 16 * 768 * 4, stream>>>(h1, W2, b2, h2, 768, 256, 1, dtf);
    r2_final<<<B / 4, 256, 0, stream>>>(h2, W3, b3, d_out, dtf);
}

// Round 3
// 1017.841 us; speedup vs baseline: 1.0496x; 1.0496x over previous
//
#include <hip/hip_runtime.h>
#include <hip/hip_bf16.h>

// All float tensors on device are FP32 (established R2: runtime dtype probe
// resolved f32; a bf16 interpretation reproduces the all-zero stub output).
#define HIDC 128

__global__ void __launch_bounds__(256) r3_zero(int* p, int n)
{
    int i = blockIdx.x * 256 + threadIdx.x;
    if (i < n) p[i] = 0;
}

// ---- wa[b] = W_b @ a_b  (row-dot), b in [0,6); block 6: c_edge = W_edge·a_edge ----
__global__ void __launch_bounds__(128) r3_wa(
    const float* __restrict__ W_dd, const float* __restrict__ W_dp, const float* __restrict__ W_cp,
    const float* __restrict__ a0, const float* __restrict__ a1, const float* __restrict__ a2,
    const float* __restrict__ a3, const float* __restrict__ a4, const float* __restrict__ a5,
    const float* __restrict__ W_edge, const float* __restrict__ a_edge,
    float* __restrict__ wa, float* __restrict__ c_edge)
{
    int b = blockIdx.x, k = threadIdx.x;
    __shared__ float as[HIDC];
    if (b < 6) {
        const float* W = (b < 2) ? W_dd : (b < 4) ? W_dp : W_cp;
        const float* a = (b == 0) ? a0 : (b == 1) ? a1 : (b == 2) ? a2 : (b == 3) ? a3 : (b == 4) ? a4 : a5;
        as[k] = a[k]; __syncthreads();
        float s = 0.f;
#pragma unroll 8
        for (int c = 0; c < HIDC; c++) s = fmaf(W[k * HIDC + c], as[c], s);
        wa[b * HIDC + k] = s;
    } else {
        as[k] = W_edge[k] * a_edge[k]; __syncthreads();
#pragma unroll
        for (int off = 64; off > 0; off >>= 1) { if (k < off) as[k] += as[k + off]; __syncthreads(); }
        if (k == 0) c_edge[0] = as[0];
    }
}

// ---- attention scalars: s = emb_row · wa  (one wave per row, 4 rows/block) ----
__global__ void __launch_bounds__(256) r3_scalars(
    const float* __restrict__ drug_emb, const float* __restrict__ prot_emb, const float* __restrict__ cell_emb,
    const int* __restrict__ x_drug, const int* __restrict__ x_prot, const int* __restrict__ x_cell,
    const float* __restrict__ wa,
    float* __restrict__ ssrc_dd, float* __restrict__ sdst_dd, float* __restrict__ sdst_dp,
    float* __restrict__ ssrc_dp, float* __restrict__ ssrc_cp, float* __restrict__ sdst_cp,
    int nd, int npr, int ncl)
{
    int g = blockIdx.x * 4 + (threadIdx.x >> 6);
    int l = threadIdx.x & 63;
    const float2* wa2 = (const float2*)wa;   // wa2[v*64 + l]
    if (g < nd) {
        int id = x_drug[g];
        float2 e = ((const float2*)drug_emb)[(size_t)id * 64 + l];
        float2 w0 = wa2[0 * 64 + l], w1 = wa2[1 * 64 + l], w3 = wa2[3 * 64 + l];
        float p0 = e.x * w0.x + e.y * w0.y;
        float p1 = e.x * w1.x + e.y * w1.y;
        float p2 = e.x * w3.x + e.y * w3.y;
#pragma unroll
        for (int off = 32; off > 0; off >>= 1) {
            p0 += __shfl_xor(p0, off, 64);
            p1 += __shfl_xor(p1, off, 64);
            p2 += __shfl_xor(p2, off, 64);
        }
        if (l == 0) { ssrc_dd[g] = p0; sdst_dd[g] = p1; sdst_dp[g] = p2; }
    } else if (g < nd + npr) {
        int r = g - nd;
        int id = x_prot[r];
        float2 e = ((const float2*)prot_emb)[(size_t)id * 64 + l];
        float2 w2 = wa2[2 * 64 + l], w4 = wa2[4 * 64 + l];
        float p0 = e.x * w2.x + e.y * w2.y;
        float p1 = e.x * w4.x + e.y * w4.y;
#pragma unroll
        for (int off = 32; off > 0; off >>= 1) {
            p0 += __shfl_xor(p0, off, 64);
            p1 += __shfl_xor(p1, off, 64);
        }
        if (l == 0) { ssrc_dp[r] = p0; ssrc_cp[r] = p1; }
    } else if (g < nd + npr + ncl) {
        int r = g - nd - npr;
        int id = x_cell[r];
        float2 e = ((const float2*)cell_emb)[(size_t)id * 64 + l];
        float2 w5 = wa2[5 * 64 + l];
        float p0 = e.x * w5.x + e.y * w5.y;
#pragma unroll
        for (int off = 32; off > 0; off >>= 1) p0 += __shfl_xor(p0, off, 64);
        if (l == 0) sdst_cp[r] = p0;
    }
}

// ---- node GEMM: H[r] = emb[idx[r]] @ W, 16 rows/block, 128 threads ----
// requires nrows % 16 == 0 (4096, 20000, 1024 all satisfy)
__global__ void __launch_bounds__(128) r3_node_gemm(
    const float* __restrict__ emb, const int* __restrict__ idx,
    const float* __restrict__ W, float* __restrict__ H)
{
    int r0 = blockIdx.x * 16;
    int tid = threadIdx.x;
    __shared__ int ids[16];
    __shared__ float xs[16 * HIDC];
    if (tid < 16) ids[tid] = idx[r0 + tid];
    __syncthreads();
    for (int t = tid; t < 16 * HIDC; t += 128) {
        int r = t >> 7, k = t & 127;
        xs[t] = emb[(size_t)ids[r] * HIDC + k];
    }
    __syncthreads();
    int c = tid;
    float acc[16];
#pragma unroll
    for (int r = 0; r < 16; r++) acc[r] = 0.f;
    for (int k = 0; k < HIDC; k += 4) {
        float w0 = W[(k + 0) * HIDC + c];
        float w1 = W[(k + 1) * HIDC + c];
        float w2 = W[(k + 2) * HIDC + c];
        float w3 = W[(k + 3) * HIDC + c];
#pragma unroll
        for (int r = 0; r < 16; r++) {
            float4 x = *(const float4*)&xs[r * HIDC + k];
            acc[r] = fmaf(x.x, w0, fmaf(x.y, w1, fmaf(x.z, w2, fmaf(x.w, w3, acc[r]))));
        }
    }
#pragma unroll
    for (int r = 0; r < 16; r++) H[(size_t)(r0 + r) * HIDC + c] = acc[r];
}

// ---- d-d preprocessing ----
__global__ void r3_dd_pre(const int* __restrict__ ei, const float* __restrict__ attr, int E,
                          int* __restrict__ deg, float* __restrict__ attr_sum)
{
    int e = blockIdx.x * 256 + threadIdx.x;
    if (e >= E) return;
    int d = ei[E + e];
    atomicAdd(&deg[d], 1);
    atomicAdd(&attr_sum[d], attr[e]);
}

__global__ void r3_dd_finalize(const int* __restrict__ deg, float* __restrict__ attr_sum,
                               int* __restrict__ cnt, int n)
{
    int d = blockIdx.x * 256 + threadIdx.x;
    if (d >= n) return;
    int dg = deg[d];
    cnt[d] = dg + 1;
    attr_sum[d] = attr_sum[d] / fmaxf((float)dg, 1.0f);
}

__global__ void r3_count(const int* __restrict__ dst, int E, int* __restrict__ cnt)
{
    int e = blockIdx.x * 256 + threadIdx.x;
    if (e >= E) return;
    atomicAdd(&cnt[dst[e]], 1);
}

// ---- three exclusive scans, one block each ----
__global__ void __launch_bounds__(1024) r3_exscan3(
    const int* __restrict__ in0, int* __restrict__ out0, int n0,
    const int* __restrict__ in1, int* __restrict__ out1, int n1,
    const int* __restrict__ in2, int* __restrict__ out2, int n2)
{
    const int* in; int* out; int n;
    if (blockIdx.x == 0)      { in = in0; out = out0; n = n0; }
    else if (blockIdx.x == 1) { in = in1; out = out1; n = n1; }
    else                      { in = in2; out = out2; n = n2; }
    __shared__ int buf[1024];
    __shared__ int carry;
    int tid = threadIdx.x;
    if (tid == 0) carry = 0;
    __syncthreads();
    for (int base = 0; base < n; base += 1024) {
        int i = base + tid;
        int v = (i < n) ? in[i] : 0;
        buf[tid] = v; __syncthreads();
        for (int off = 1; off < 1024; off <<= 1) {
            int t = (tid >= off) ? buf[tid - off] : 0;
            __syncthreads();
            buf[tid] += t;
            __syncthreads();
        }
        int c0 = carry;
        int incl = buf[tid];
        if (i < n) out[i] = c0 + incl - v;
        __syncthreads();
        if (tid == 1023) carry = c0 + buf[1023];
        __syncthreads();
    }
    if (tid == 0) out[n] = carry;
}

// ---- CSR fill ----
__global__ void r3_fill_edges(const int* __restrict__ src, const int* __restrict__ dst, int E,
                              const float* __restrict__ s_src, const float* __restrict__ s_dst,
                              const float* __restrict__ attr, int use_attr,
                              const float* __restrict__ c_edge_ptr,
                              const int* __restrict__ row_start, int* __restrict__ cursor,
                              int* __restrict__ csr_src, float* __restrict__ csr_e)
{
    int e = blockIdx.x * 256 + threadIdx.x;
    if (e >= E) return;
    int s = src[e], d = dst[e];
    float ev = s_src[s] + s_dst[d];
    if (use_attr) ev += attr[e] * c_edge_ptr[0];
    ev = (ev > 0.f) ? ev : 0.2f * ev;
    int slot = row_start[d] + atomicAdd(&cursor[d], 1);
    csr_src[slot] = s;
    csr_e[slot] = ev;
}

__global__ void r3_fill_self(int n, const float* __restrict__ s_src, const float* __restrict__ s_dst,
                             const float* __restrict__ mean_attr, const float* __restrict__ c_edge_ptr,
                             const int* __restrict__ row_start, int* __restrict__ cursor,
                             int* __restrict__ csr_src, float* __restrict__ csr_e)
{
    int d = blockIdx.x * 256 + threadIdx.x;
    if (d >= n) return;
    float ev = s_src[d] + s_dst[d] + mean_attr[d] * c_edge_ptr[0];
    ev = (ev > 0.f) ? ev : 0.2f * ev;
    int slot = row_start[d] + atomicAdd(&cursor[d], 1);
    csr_src[slot] = d;
    csr_e[slot] = ev;
}

// ---- per-dst softmax + aggregate ----
__global__ void __launch_bounds__(128) r3_gat_aggregate(
    const int* __restrict__ row_start, const int* __restrict__ csr_src, const float* __restrict__ csr_e,
    const float* __restrict__ H, float* __restrict__ out)
{
    int row = blockIdx.x;
    int c = threadIdx.x;
    int s = row_start[row], e = row_start[row + 1];
    __shared__ float red[HIDC];
    __shared__ float se[HIDC];
    __shared__ int ss[HIDC];
    float m = -INFINITY;
    for (int i = s + c; i < e; i += HIDC) m = fmaxf(m, csr_e[i]);
    red[c] = m; __syncthreads();
#pragma unroll
    for (int off = 64; off > 0; off >>= 1) { if (c < off) red[c] = fmaxf(red[c], red[c + off]); __syncthreads(); }
    m = red[0]; __syncthreads();
    float sum = 0.f;
    for (int i = s + c; i < e; i += HIDC) sum += __expf(csr_e[i] - m);
    red[c] = sum; __syncthreads();
#pragma unroll
    for (int off = 64; off > 0; off >>= 1) { if (c < off) red[c] += red[c + off]; __syncthreads(); }
    float denom = red[0]; __syncthreads();
    float acc = 0.f;
    for (int base = s; base < e; base += HIDC) {
        int i = base + c;
        if (i < e) { se[c] = __expf(csr_e[i] - m); ss[c] = csr_src[i]; }
        __syncthreads();
        int lim = min(HIDC, e - base);
        for (int j = 0; j < lim; j++)
            acc = fmaf(se[j], H[(size_t)ss[j] * HIDC + c], acc);
        __syncthreads();
    }
    out[(size_t)row * HIDC + c] = acc / (denom + 1e-16f);
}

// ---- combine + relu + L2 normalize ----
__global__ void __launch_bounds__(128) r3_fuse_drug(
    const float* __restrict__ agg_dd, const float* __restrict__ bias_dd,
    const float* __restrict__ agg_dp, const float* __restrict__ bias_dp,
    float* __restrict__ outN)
{
    int d = blockIdx.x, c = threadIdx.x;
    float v = agg_dd[(size_t)d * HIDC + c] + bias_dd[c] + agg_dp[(size_t)d * HIDC + c] + bias_dp[c];
    v = fmaxf(v, 0.f);
    __shared__ float red[HIDC];
    red[c] = v * v; __syncthreads();
#pragma unroll
    for (int off = 64; off > 0; off >>= 1) { if (c < off) red[c] += red[c + off]; __syncthreads(); }
    float nrm = fmaxf(sqrtf(red[0]), 1e-12f);
    outN[(size_t)d * HIDC + c] = v / nrm;
}

__global__ void __launch_bounds__(128) r3_fuse_cell(
    const float* __restrict__ agg_cp, const float* __restrict__ bias_cp, float* __restrict__ outN)
{
    int d = blockIdx.x, c = threadIdx.x;
    float v = agg_cp[(size_t)d * HIDC + c] + bias_cp[c];
    v = fmaxf(v, 0.f);
    __shared__ float red[HIDC];
    red[c] = v * v; __syncthreads();
#pragma unroll
    for (int off = 64; off > 0; off >>= 1) { if (c < off) red[c] += red[c + off]; __syncthreads(); }
    float nrm = fmaxf(sqrtf(red[0]), 1e-12f);
    outN[(size_t)d * HIDC + c] = v / nrm;
}

// ---- hid gather ----
__global__ void __launch_bounds__(128) r3_gather_hid(
    const float* __restrict__ drugN, const float* __restrict__ cellN,
    const int* __restrict__ d1, const int* __restrict__ d2, const int* __restrict__ ce,
    float* __restrict__ hid)
{
    int b = blockIdx.x, c = threadIdx.x;
    hid[(size_t)b * 384 + c]       = drugN[(size_t)d1[b] * HIDC + c];
    hid[(size_t)b * 384 + 128 + c] = drugN[(size_t)d2[b] * HIDC + c];
    hid[(size_t)b * 384 + 256 + c] = cellN[(size_t)ce[b] * HIDC + c];
}

// ---- MLP GEMM: 16 rows/block, 256 threads, COLS cols/thread; linear LDS (no conflicts) ----
template <int COLS>
__global__ void __launch_bounds__(256) r3_mlp(
    const float* __restrict__ X, const float* __restrict__ W, const float* __restrict__ bias,
    float* __restrict__ Y, int K, int N, int do_relu)
{
    extern __shared__ float xs[];   // [16][K] linear
    int r0 = blockIdx.x * 16;
    for (int t = threadIdx.x; t < 16 * K; t += 256) xs[t] = X[(size_t)r0 * K + t];
    __syncthreads();
    int c = threadIdx.x;
    float acc[16][COLS];
#pragma unroll
    for (int r = 0; r < 16; r++)
#pragma unroll
        for (int j = 0; j < COLS; j++) acc[r][j] = 0.f;

    for (int k = 0; k < K; k += 4) {
        float w[4][COLS];
#pragma unroll
        for (int kk = 0; kk < 4; kk++)
#pragma unroll
            for (int j = 0; j < COLS; j++) w[kk][j] = W[(size_t)(k + kk) * N + c + j * 256];
#pragma unroll
        for (int r = 0; r < 16; r++) {
            float4 x = *(const float4*)&xs[r * K + k];
#pragma unroll
            for (int j = 0; j < COLS; j++)
                acc[r][j] = fmaf(x.x, w[0][j], fmaf(x.y, w[1][j], fmaf(x.z, w[2][j], fmaf(x.w, w[3][j], acc[r][j]))));
        }
    }
#pragma unroll
    for (int j = 0; j < COLS; j++) {
        float bv = bias[c + j * 256];
#pragma unroll
        for (int r = 0; r < 16; r++) {
            float v = acc[r][j] + bv;
            if (do_relu) v = fmaxf(v, 0.f);
            Y[(size_t)(r0 + r) * N + c + j * 256] = v;
        }
    }
}

// ---- final 256->2, wave per row, fp32 out ----
__global__ void __launch_bounds__(256) r3_final(
    const float* __restrict__ h2, const float* __restrict__ W3, const float* __restrict__ b3,
    float* __restrict__ out)
{
    int row = blockIdx.x * 4 + (threadIdx.x >> 6);
    int lane = threadIdx.x & 63;
    float a0 = 0.f, a1 = 0.f;
    for (int k = lane; k < 256; k += 64) {
        float h = h2[(size_t)row * 256 + k];
        a0 = fmaf(h, W3[k * 2 + 0], a0);
        a1 = fmaf(h, W3[k * 2 + 1], a1);
    }
#pragma unroll
    for (int off = 32; off > 0; off >>= 1) {
        a0 += __shfl_down(a0, off, 64);
        a1 += __shfl_down(a1, off, 64);
    }
    if (lane == 0) {
        out[row * 2 + 0] = a0 + b3[0];
        out[row * 2 + 1] = a1 + b3[1];
    }
}

extern "C" void kernel_launch(void* const* d_in, const int* in_sizes, int n_in,
                              void* d_out, int out_size, void* d_ws, size_t ws_size,
                              hipStream_t stream)
{
    const int* x_drug      = (const int*)d_in[0];
    const int* x_protein   = (const int*)d_in[1];
    const int* x_cell      = (const int*)d_in[2];
    const int* ei_dd       = (const int*)d_in[3];
    const float* attr_dd   = (const float*)d_in[4];
    const int* src_dp      = (const int*)d_in[5];
    const int* dst_dp      = (const int*)d_in[6];
    const int* src_cp      = (const int*)d_in[7];
    const int* dst_cp      = (const int*)d_in[8];
    const int* drug1       = (const int*)d_in[9];
    const int* drug2       = (const int*)d_in[10];
    const int* cellb       = (const int*)d_in[11];
    const float* drug_emb  = (const float*)d_in[12];
    const float* protein_emb = (const float*)d_in[13];
    const float* cell_emb  = (const float*)d_in[14];
    const float* W_dd      = (const float*)d_in[15];
    const float* a_src_dd  = (const float*)d_in[16];
    const float* a_dst_dd  = (const float*)d_in[17];
    const float* bias_dd   = (const float*)d_in[18];
    const float* W_edge_dd = (const float*)d_in[19];
    const float* a_edge_dd = (const float*)d_in[20];
    const float* W_dp      = (const float*)d_in[21];
    const float* a_src_dp  = (const float*)d_in[22];
    const float* a_dst_dp  = (const float*)d_in[23];
    const float* bias_dp   = (const float*)d_in[24];
    const float* W_cp      = (const float*)d_in[25];
    const float* a_src_cp  = (const float*)d_in[26];
    const float* a_dst_cp  = (const float*)d_in[27];
    const float* bias_cp   = (const float*)d_in[28];
    const float* W1        = (const float*)d_in[29];
    const float* b1        = (const float*)d_in[30];
    const float* W2        = (const float*)d_in[31];
    const float* b2        = (const float*)d_in[32];
    const float* W3        = (const float*)d_in[33];
    const float* b3        = (const float*)d_in[34];

    const int ND  = in_sizes[0];
    const int NPR = in_sizes[1];
    const int NCL = in_sizes[2];
    const int E_DD = in_sizes[4];
    const int E_DP = in_sizes[5];
    const int E_CP = in_sizes[7];
    const int B    = in_sizes[9];
    const int E_DD2 = E_DD + ND;

    // ---- carve workspace ----
    char* p = (char*)d_ws;
    auto carve = [&](size_t bytes) -> char* {
        char* r = p;
        p += (bytes + 255) & ~(size_t)255;
        return r;
    };
    // zeroed region
    char* zstart = p;
    int*   deg      = (int*)  carve((size_t)ND * 4);
    float* attr_sum = (float*)carve((size_t)ND * 4);
    int*   cnt_dp   = (int*)  carve((size_t)ND * 4);
    int*   cnt_cp   = (int*)  carve((size_t)NCL * 4);
    int*   cur_dd   = (int*)  carve((size_t)ND * 4);
    int*   cur_dp   = (int*)  carve((size_t)ND * 4);
    int*   cur_cp   = (int*)  carve((size_t)NCL * 4);
    size_t zbytes = (size_t)(p - zstart);
    // non-zeroed
    int*   cnt_dd   = (int*)  carve((size_t)ND * 4);
    int*   rs_dd    = (int*)  carve((size_t)(ND + 1) * 4);
    int*   rs_dp    = (int*)  carve((size_t)(ND + 1) * 4);
    int*   rs_cp    = (int*)  carve((size_t)(NCL + 1) * 4);
    float* c_edge   = (float*)carve(256);
    float* wa       = (float*)carve(6 * HIDC * 4);
    float* H_dd     = (float*)carve((size_t)ND * HIDC * 4);
    float* H_dp     = (float*)carve((size_t)NPR * HIDC * 4);
    float* H_cp     = (float*)carve((size_t)NPR * HIDC * 4);
    float* ssrc_dd  = (float*)carve((size_t)ND * 4);
    float* sdst_dd  = (float*)carve((size_t)ND * 4);
    float* ssrc_dp  = (float*)carve((size_t)NPR * 4);
    float* sdst_dp  = (float*)carve((size_t)ND * 4);
    float* ssrc_cp  = (float*)carve((size_t)NPR * 4);
    float* sdst_cp  = (float*)carve((size_t)NCL * 4);
    int*   csrc_dd  = (int*)  carve((size_t)E_DD2 * 4);
    float* ce_dd    = (float*)carve((size_t)E_DD2 * 4);
    int*   csrc_dp  = (int*)  carve((size_t)E_DP * 4);
    float* ce_dp    = (float*)carve((size_t)E_DP * 4);
    int*   csrc_cp  = (int*)  carve((size_t)E_CP * 4);
    float* ce_cp    = (float*)carve((size_t)E_CP * 4);
    float* agg_dd   = (float*)carve((size_t)ND * HIDC * 4);
    float* agg_dp   = (float*)carve((size_t)ND * HIDC * 4);
    float* agg_cp   = (float*)carve((size_t)NCL * HIDC * 4);
    float* drugN    = (float*)carve((size_t)ND * HIDC * 4);
    float* cellN    = (float*)carve((size_t)NCL * HIDC * 4);
    float* hid      = (float*)carve((size_t)B * 384 * 4);
    float* h1       = (float*)carve((size_t)B * 768 * 4);
    float* h2       = hid;  // hid dead after MLP layer 1; B*256 <= B*384

    auto cdiv = [](int a, int b) { return (a + b - 1) / b; };

    // ---- init + precompute ----
    int zwords = (int)(zbytes / 4);
    r3_zero<<<cdiv(zwords, 256), 256, 0, stream>>>((int*)zstart, zwords);
    r3_wa<<<7, 128, 0, stream>>>(W_dd, W_dp, W_cp,
                                 a_src_dd, a_dst_dd, a_src_dp, a_dst_dp, a_src_cp, a_dst_cp,
                                 W_edge_dd, a_edge_dd, wa, c_edge);

    // ---- node GEMMs (H only) + attention scalars ----
    r3_node_gemm<<<ND / 16, 128, 0, stream>>>(drug_emb, x_drug, W_dd, H_dd);
    r3_node_gemm<<<NPR / 16, 128, 0, stream>>>(protein_emb, x_protein, W_dp, H_dp);
    r3_node_gemm<<<NPR / 16, 128, 0, stream>>>(protein_emb, x_protein, W_cp, H_cp);
    r3_scalars<<<(ND + NPR + NCL) / 4, 256, 0, stream>>>(
        drug_emb, protein_emb, cell_emb, x_drug, x_protein, x_cell, wa,
        ssrc_dd, sdst_dd, sdst_dp, ssrc_dp, ssrc_cp, sdst_cp, ND, NPR, NCL);

    // ---- degrees / counts ----
    r3_dd_pre<<<cdiv(E_DD, 256), 256, 0, stream>>>(ei_dd, attr_dd, E_DD, deg, attr_sum);
    r3_dd_finalize<<<cdiv(ND, 256), 256, 0, stream>>>(deg, attr_sum, cnt_dd, ND);
    r3_count<<<cdiv(E_DP, 256), 256, 0, stream>>>(dst_dp, E_DP, cnt_dp);
    r3_count<<<cdiv(E_CP, 256), 256, 0, stream>>>(dst_cp, E_CP, cnt_cp);

    // ---- CSR row starts (3 scans in one kernel) ----
    r3_exscan3<<<3, 1024, 0, stream>>>(cnt_dd, rs_dd, ND, cnt_dp, rs_dp, ND, cnt_cp, rs_cp, NCL);

    // ---- CSR fill ----
    r3_fill_edges<<<cdiv(E_DD, 256), 256, 0, stream>>>(ei_dd, ei_dd + E_DD, E_DD, ssrc_dd, sdst_dd,
                                                       attr_dd, 1, c_edge, rs_dd, cur_dd, csrc_dd, ce_dd);
    r3_fill_self<<<cdiv(ND, 256), 256, 0, stream>>>(ND, ssrc_dd, sdst_dd, attr_sum, c_edge,
                                                    rs_dd, cur_dd, csrc_dd, ce_dd);
    r3_fill_edges<<<cdiv(E_DP, 256), 256, 0, stream>>>(src_dp, dst_dp, E_DP, ssrc_dp, sdst_dp,
                                                       nullptr, 0, c_edge, rs_dp, cur_dp, csrc_dp, ce_dp);
    r3_fill_edges<<<cdiv(E_CP, 256), 256, 0, stream>>>(src_cp, dst_cp, E_CP, ssrc_cp, sdst_cp,
                                                       nullptr, 0, c_edge, rs_cp, cur_cp, csrc_cp, ce_cp);

    // ---- softmax + aggregate ----
    r3_gat_aggregate<<<ND, 128, 0, stream>>>(rs_dd, csrc_dd, ce_dd, H_dd, agg_dd);
    r3_gat_aggregate<<<ND, 128, 0, stream>>>(rs_dp, csrc_dp, ce_dp, H_dp, agg_dp);
    r3_gat_aggregate<<<NCL, 128, 0, stream>>>(rs_cp, csrc_cp, ce_cp, H_cp, agg_cp);

    // ---- combine + relu + L2 normalize ----
    r3_fuse_drug<<<ND, 128, 0, stream>>>(agg_dd, bias_dd, agg_dp, bias_dp, drugN);
    r3_fuse_cell<<<NCL, 128, 0, stream>>>(agg_cp, bias_cp, cellN);

    // ---- batch gather + MLP ----
    r3_gather_hid<<<B, 128, 0, stream>>>(drugN, cellN, drug1, drug2, cellb, hid);
    r3_mlp<3><<<B / 16, 256, 16 * 384 * 4, stream>>>(hid, W1, b1, h1, 384, 768, 1);
    r3_mlp<1><<<B / 16, 256, 16 * 768 * 4, stream>>>(h1, W2, b2, h2, 768, 256, 1);
    r3_final<<<B / 4, 256, 0, stream>>>(h2, W3, b3, (float*)d_out);
}